// Round 5
// baseline (263.863 us; speedup 1.0000x reference)
//
#include <hip/hip_runtime.h>

typedef _Float16 f16x8 __attribute__((ext_vector_type(8)));
typedef _Float16 f16x2 __attribute__((ext_vector_type(2)));
typedef float f32x4 __attribute__((ext_vector_type(4)));
typedef int i32x4 __attribute__((ext_vector_type(4)));

#define MFMA16(a, b, c) __builtin_amdgcn_mfma_f32_16x16x32_f16(a, b, c, 0, 0, 0)

#define NROW 65536           // 256*256 rows
#define SEGB 16777216ull     // 16MB workspace segment
#define LOG2E 1.4426950408889634f

// ---------------------------------------------------------------------------
// Kernel 1: LayerNorm (fp32) -> z_ln f16 ; bias = z_ln @ Wb, stored j-major
// pre-scaled by log2(e):  biasT[h][j*256 + k] = bias[j][k]*log2e
// (j-major lets attn lanes load float4 of 4 consecutive k).
// Blocks >= 16384 transpose+convert the 5 weight mats to f16 Wt[n][k].
// ---------------------------------------------------------------------------
__global__ __launch_bounds__(256) void k_ln(
    const float* __restrict__ z, const float* __restrict__ gamma,
    const float* __restrict__ beta, const float* __restrict__ Wb,
    const float* __restrict__ Wq, const float* __restrict__ Wk,
    const float* __restrict__ Wv, const float* __restrict__ Wg,
    const float* __restrict__ Wout,
    _Float16* __restrict__ zln, float* __restrict__ biasT,
    _Float16* __restrict__ WtAll)
{
  __shared__ _Float16 sw[32 * 136];
  int bid = blockIdx.x;
  if (bid < 16384) {
    int lane = threadIdx.x & 63;
    int w = threadIdx.x >> 6;
    int row = bid * 4 + w;
    float2 v = ((const float2*)(z + (size_t)row * 128))[lane];
    float s = v.x + v.y;
    #pragma unroll
    for (int m = 1; m < 64; m <<= 1) s += __shfl_xor(s, m);
    float mu = s * 0.0078125f;
    float dx = v.x - mu, dy = v.y - mu;
    float q = dx * dx + dy * dy;
    #pragma unroll
    for (int m = 1; m < 64; m <<= 1) q += __shfl_xor(q, m);
    float rs = rsqrtf(q * 0.0078125f + 1e-5f);
    float2 g2 = ((const float2*)gamma)[lane];
    float2 b2 = ((const float2*)beta)[lane];
    float y0 = dx * rs * g2.x + b2.x;
    float y1 = dy * rs * g2.y + b2.y;
    f16x2 pr; pr.x = (_Float16)y0; pr.y = (_Float16)y1;
    *(f16x2*)(zln + (size_t)row * 128 + 2 * lane) = pr;
    // bias = y . Wb[:,h]  (Wb row-major [128][4] -> float4 per row)
    float4 wb0 = ((const float4*)Wb)[2 * lane];
    float4 wb1 = ((const float4*)Wb)[2 * lane + 1];
    float pb0 = y0 * wb0.x + y1 * wb1.x;
    float pb1 = y0 * wb0.y + y1 * wb1.y;
    float pb2 = y0 * wb0.z + y1 * wb1.z;
    float pb3 = y0 * wb0.w + y1 * wb1.w;
    #pragma unroll
    for (int m = 1; m < 64; m <<= 1) {
      pb0 += __shfl_xor(pb0, m);
      pb1 += __shfl_xor(pb1, m);
      pb2 += __shfl_xor(pb2, m);
      pb3 += __shfl_xor(pb3, m);
    }
    if (lane == 0) {
      // row = j*256 + k ; store j-major, *log2e
      biasT[row] = pb0 * LOG2E;
      biasT[NROW + row] = pb1 * LOG2E;
      biasT[2 * NROW + row] = pb2 * LOG2E;
      biasT[3 * NROW + row] = pb3 * LOG2E;
    }
  } else {
    // weight transpose+convert: Wt_m[n][k] = W_m[k][n], f16
    int t = bid - 16384;            // 0..19 : 5 mats x 4 slabs of 32 n
    int mat = t >> 2, n0 = (t & 3) * 32;
    const float* src = (mat == 0) ? Wq : (mat == 1) ? Wk : (mat == 2) ? Wv
                       : (mat == 3) ? Wg : Wout;
    _Float16* dst = WtAll + mat * 16384;
    for (int it = 0; it < 16; ++it) {
      int e = threadIdx.x + it * 256;   // 4096 elems
      int c = e >> 5, j = e & 31;
      sw[j * 136 + c] = (_Float16)src[c * 128 + n0 + j];
    }
    __syncthreads();
    for (int it = 0; it < 2; ++it) {
      int ch = threadIdx.x + it * 256;  // 512 chunks of 8
      int n = ch >> 4, k8 = (ch & 15) * 8;
      *(int4*)(dst + (n0 + n) * 128 + k8) = *(const int4*)&sw[n * 136 + k8];
    }
  }
}

// ---------------------------------------------------------------------------
// Kernel 2: projections  out = z_ln @ W  for W in {Wq,Wk,Wv,Wg}, sigmoid
// fused for Wg.  128x128 tile, K=128 one shot, 4 waves of 64x64.
// Grid is 1-D 2048 with XCD-aware decode: the 4 by-variants of each m-tile
// get ids that are congruent mod 8 -> same XCD -> A-tile read once from HBM,
// 3x from that XCD's L2.
// ---------------------------------------------------------------------------
__global__ __launch_bounds__(256) void k_proj(
    const _Float16* __restrict__ A, const _Float16* __restrict__ WtAll,
    _Float16* __restrict__ Qb, _Float16* __restrict__ Kb,
    _Float16* __restrict__ Vb, _Float16* __restrict__ Gb)
{
  __shared__ _Float16 sA[128 * 136];
  __shared__ _Float16 sB[128 * 136];
  int e = blockIdx.x;                 // 0..2047
  int by = (e >> 3) & 3;              // mat select
  int xb = ((e >> 5) << 3) | (e & 7); // m-tile, ids {g*32+by*8+xcd} share xcd
  int m0 = xb * 128;
  const _Float16* Bt = WtAll + by * 16384;
  _Float16* outp = (by == 0) ? Qb : (by == 1) ? Kb : (by == 2) ? Vb : Gb;
  int tid = threadIdx.x;
  for (int it = 0; it < 8; ++it) {
    int ch = tid + it * 256;           // 2048 chunks of 8 halfs
    int r = ch >> 4, c8 = (ch & 15) * 8;
    *(int4*)&sA[r * 136 + c8] = *(const int4*)(A + (size_t)(m0 + r) * 128 + c8);
    *(int4*)&sB[r * 136 + c8] = *(const int4*)(Bt + r * 128 + c8);
  }
  __syncthreads();
  int lane = tid & 63, w = tid >> 6;
  int mw = (w >> 1) * 64, nw = (w & 1) * 64;
  int lr = lane & 15, lg = lane >> 4;
  f32x4 z4 = {0.f, 0.f, 0.f, 0.f};
  f32x4 acc[4][4];
  #pragma unroll
  for (int mt = 0; mt < 4; ++mt)
    #pragma unroll
    for (int nt = 0; nt < 4; ++nt) acc[mt][nt] = z4;
  #pragma unroll
  for (int k0 = 0; k0 < 128; k0 += 32) {
    f16x8 af[4], bf[4];
    #pragma unroll
    for (int mt = 0; mt < 4; ++mt)
      af[mt] = *(const f16x8*)&sA[(mw + mt * 16 + lr) * 136 + k0 + lg * 8];
    #pragma unroll
    for (int nt = 0; nt < 4; ++nt)
      bf[nt] = *(const f16x8*)&sB[(nw + nt * 16 + lr) * 136 + k0 + lg * 8];
    #pragma unroll
    for (int mt = 0; mt < 4; ++mt)
      #pragma unroll
      for (int nt = 0; nt < 4; ++nt)
        acc[mt][nt] = MFMA16(af[mt], bf[nt], acc[mt][nt]);
  }
  bool sig = (by == 3);
  #pragma unroll
  for (int mt = 0; mt < 4; ++mt)
    #pragma unroll
    for (int nt = 0; nt < 4; ++nt)
      #pragma unroll
      for (int r = 0; r < 4; ++r) {
        int row = m0 + mw + mt * 16 + lg * 4 + r;
        int col = nw + nt * 16 + lr;
        float v = acc[mt][nt][r];
        if (sig) v = 1.0f / (1.0f + __expf(-v));
        outp[(size_t)row * 128 + col] = (_Float16)v;
      }
}

// ---------------------------------------------------------------------------
// Kernel 3: attention per (i,h).  Swapped-operand scores S^T = mfma(K, Q):
// k on C-rows, j on C-cols -> lane owns a k-slice of ONE j column.
// ONLINE softmax over two 128-k chunks: only sacc[8] (32 regs) live at a
// time.  Chunk-1 rescale is UNCONDITIONAL (round-4 bug: the rescale
// condition was per-lane/per-column, but each lane's oacc rows belong to
// OTHER lanes' columns -> divergent shfl + skipped multiplies).  f==1.0
// when no rescale needed, so unconditional is both correct and cheap.
// exp2/pack/shuffle fused into PV; normalization deferred to epilogue.
// __launch_bounds__(256,4) caps at 128 regs (need ~90; falsifier:
// WRITE_SIZE must stay 16.4MB).  LDS 32KB -> 4 blocks/CU resident.
// ---------------------------------------------------------------------------
__global__ __launch_bounds__(256, 4) void k_attn(
    const _Float16* __restrict__ Qb, const _Float16* __restrict__ Kb,
    const _Float16* __restrict__ Vb, const _Float16* __restrict__ Gb,
    const float* __restrict__ biasT, _Float16* __restrict__ OG)
{
  __shared__ _Float16 sK[256 * 32];   // [k][d], chunk-swizzled
  __shared__ _Float16 sV[32 * 256];   // Vt [d][k], chunk-swizzled
  int i = blockIdx.x, h = blockIdx.y;
  int tid = threadIdx.x;
  size_t base = ((size_t)i * 256) * 128 + h * 32;
  // stage K: row r, chunk cx -> phys cx ^ ((r>>1)&3)
  for (int it = 0; it < 4; ++it) {
    int ch = tid + it * 256;          // 1024 chunks
    int r = ch >> 2, cx = ch & 3;
    int p = cx ^ ((r >> 1) & 3);
    *(int4*)&sK[r * 32 + p * 8] = *(const int4*)(Kb + base + (size_t)r * 128 + cx * 8);
  }
  // stage V transposed: Vt[d][k], chunk (k>>3) -> phys ^ (d&7)
  for (int it = 0; it < 4; ++it) {
    int ch = tid + it * 256;
    int k = ch >> 2, d8 = (ch & 3) * 8;
    f16x8 tv = *(const f16x8*)(Vb + base + (size_t)k * 128 + d8);
    #pragma unroll
    for (int jj = 0; jj < 8; ++jj) {
      int d = d8 + jj;
      int p = (k >> 3) ^ (d & 7);
      sV[d * 256 + p * 8 + (k & 7)] = tv[jj];
    }
  }
  __syncthreads();
  int lane = tid & 63, w = tid >> 6;
  int lr = lane & 15, lg = lane >> 4;
  const float scale = 0.2550348858f;  // log2(e)/sqrt(32)
  f32x4 z4 = {0.f, 0.f, 0.f, 0.f};
  // P-redistribution lane constants:
  //   within a 32-k window, target elem k=8lg+e lives at lane la=lr+32(lg&1)
  //   (e<4) / la+16 (e>=4), word pair selected by hi=lg>>1.
  int la = lr + ((lg & 1) << 5);
  int lb = la + 16;
  int hi = lg >> 1;
  for (int pass = 0; pass < 4; ++pass) {
    int jbase = pass * 64;
    int jg = jbase + (w << 4) + lr;   // this lane's j (C-column)
    // Q fragment straight from global (each row used once); enters as B operand
    f16x8 aq = *(const f16x8*)(Qb + base + (size_t)jg * 128 + lg * 8);
    const float* bp = biasT + ((size_t)h << 16) + ((size_t)jg << 8) + (lg << 2);
    float m_run = -1e30f, sum = 0.f;
    f32x4 oacc[2] = {z4, z4};
    #pragma unroll
    for (int cch = 0; cch < 2; ++cch) {
      // QK^T for this 128-k chunk
      f32x4 sacc[8];
      __builtin_amdgcn_s_setprio(1);
      #pragma unroll
      for (int kt = 0; kt < 8; ++kt) {
        int r = cch * 128 + kt * 16 + lr;
        int p = lg ^ ((r >> 1) & 3);
        f16x8 bk = *(const f16x8*)&sK[r * 32 + p * 8];
        sacc[kt] = MFMA16(bk, aq, z4);  // A=K rows, B=Q rows -> C[k][j]
      }
      __builtin_amdgcn_s_setprio(0);
      // scale + bias (j-major, pre-scaled by log2e) + chunk max
      float cmx = -1e30f;
      #pragma unroll
      for (int kt = 0; kt < 8; ++kt) {
        float4 b4 = *(const float4*)(bp + (cch * 8 + kt) * 16);
        sacc[kt][0] = sacc[kt][0] * scale + b4.x;
        sacc[kt][1] = sacc[kt][1] * scale + b4.y;
        sacc[kt][2] = sacc[kt][2] * scale + b4.z;
        sacc[kt][3] = sacc[kt][3] * scale + b4.w;
        cmx = fmaxf(cmx, fmaxf(fmaxf(sacc[kt][0], sacc[kt][1]),
                               fmaxf(sacc[kt][2], sacc[kt][3])));
      }
      cmx = fmaxf(cmx, __shfl_xor(cmx, 16));
      cmx = fmaxf(cmx, __shfl_xor(cmx, 32));
      if (cch == 0) {
        m_run = cmx;                  // first chunk: oacc/sum are zero
      } else {
        // UNCONDITIONAL rescale: all 64 lanes execute (f==1 if no change).
        // oacc rows belong to column lg*4+r whose softmax state lives in
        // lane lg*4+r -> broadcast per-row factors from owning lanes.
        float mnew = fmaxf(m_run, cmx);
        float f = exp2f(m_run - mnew);
        m_run = mnew;
        sum *= f;
        float f0 = __shfl(f, (lg << 2));
        float f1 = __shfl(f, (lg << 2) + 1);
        float f2 = __shfl(f, (lg << 2) + 2);
        float f3 = __shfl(f, (lg << 2) + 3);
        oacc[0][0] *= f0; oacc[0][1] *= f1; oacc[0][2] *= f2; oacc[0][3] *= f3;
        oacc[1][0] *= f0; oacc[1][1] *= f1; oacc[1][2] *= f2; oacc[1][3] *= f3;
      }
      // fused exp2 + pack + lane-exchange + PV MFMA (sacc retires here)
      #pragma unroll
      for (int ks = 0; ks < 4; ++ks) {
        float p0 = exp2f(sacc[2 * ks][0] - m_run);
        float p1 = exp2f(sacc[2 * ks][1] - m_run);
        float p2 = exp2f(sacc[2 * ks][2] - m_run);
        float p3 = exp2f(sacc[2 * ks][3] - m_run);
        float p4 = exp2f(sacc[2 * ks + 1][0] - m_run);
        float p5 = exp2f(sacc[2 * ks + 1][1] - m_run);
        float p6 = exp2f(sacc[2 * ks + 1][2] - m_run);
        float p7 = exp2f(sacc[2 * ks + 1][3] - m_run);
        sum += ((p0 + p1) + (p2 + p3)) + ((p4 + p5) + (p6 + p7));
        f16x2 wA0, wA1, wB0, wB1;
        wA0.x = (_Float16)p0; wA0.y = (_Float16)p1;
        wA1.x = (_Float16)p2; wA1.y = (_Float16)p3;
        wB0.x = (_Float16)p4; wB0.y = (_Float16)p5;
        wB1.x = (_Float16)p6; wB1.y = (_Float16)p7;
        int A0 = __builtin_bit_cast(int, wA0);
        int A1 = __builtin_bit_cast(int, wA1);
        int B0 = __builtin_bit_cast(int, wB0);
        int B1 = __builtin_bit_cast(int, wB1);
        int a0 = __shfl(A0, la);
        int a1 = __shfl(A1, la);
        int c0 = __shfl(B0, la);
        int c1 = __shfl(B1, la);
        int b0 = __shfl(A0, lb);
        int b1 = __shfl(A1, lb);
        int d0 = __shfl(B0, lb);
        int d1 = __shfl(B1, lb);
        i32x4 wv;
        wv.x = hi ? c0 : a0;
        wv.y = hi ? c1 : a1;
        wv.z = hi ? d0 : b0;
        wv.w = hi ? d1 : b1;
        f16x8 ap = __builtin_bit_cast(f16x8, wv);
        __builtin_amdgcn_s_setprio(1);
        #pragma unroll
        for (int nt = 0; nt < 2; ++nt) {
          int d = nt * 16 + lr;
          int c = cch * 16 + ks * 4 + lg;
          f16x8 bv = *(const f16x8*)&sV[d * 256 + (c ^ (d & 7)) * 8];
          oacc[nt] = MFMA16(ap, bv, oacc[nt]);
        }
        __builtin_amdgcn_s_setprio(0);
      }
    }
    sum += __shfl_xor(sum, 16);
    sum += __shfl_xor(sum, 32);
    float rinv = 1.0f / sum;          // deferred normalization (fold into gate)
    float rr0 = __shfl(rinv, (lg << 2));
    float rr1 = __shfl(rinv, (lg << 2) + 1);
    float rr2 = __shfl(rinv, (lg << 2) + 2);
    float rr3 = __shfl(rinv, (lg << 2) + 3);
    // gate with G (sigmoid already applied), normalize, store
    float rrs[4] = {rr0, rr1, rr2, rr3};
    #pragma unroll
    for (int nt = 0; nt < 2; ++nt)
      #pragma unroll
      for (int r = 0; r < 4; ++r) {
        int j = jbase + (w << 4) + (lg << 2) + r;
        int d = nt * 16 + lr;
        size_t idx = base + (size_t)j * 128 + d;
        float g = (float)Gb[idx];
        OG[idx] = (_Float16)(oacc[nt][r] * rrs[r] * g);
      }
  }
}

// ---------------------------------------------------------------------------
// Kernel 4: out = OG @ Wout  (fp32 output)
// ---------------------------------------------------------------------------
__global__ __launch_bounds__(256) void k_outp(
    const _Float16* __restrict__ A, const _Float16* __restrict__ Bt,
    float* __restrict__ out)
{
  __shared__ _Float16 sA[128 * 136];
  __shared__ _Float16 sB[128 * 136];
  int m0 = blockIdx.x * 128;
  int tid = threadIdx.x;
  for (int it = 0; it < 8; ++it) {
    int ch = tid + it * 256;
    int r = ch >> 4, c8 = (ch & 15) * 8;
    *(int4*)&sA[r * 136 + c8] = *(const int4*)(A + (size_t)(m0 + r) * 128 + c8);
    *(int4*)&sB[r * 136 + c8] = *(const int4*)(Bt + r * 128 + c8);
  }
  __syncthreads();
  int lane = tid & 63, w = tid >> 6;
  int mw = (w >> 1) * 64, nw = (w & 1) * 64;
  int lr = lane & 15, lg = lane >> 4;
  f32x4 z4 = {0.f, 0.f, 0.f, 0.f};
  f32x4 acc[4][4];
  #pragma unroll
  for (int mt = 0; mt < 4; ++mt)
    #pragma unroll
    for (int nt = 0; nt < 4; ++nt) acc[mt][nt] = z4;
  #pragma unroll
  for (int k0 = 0; k0 < 128; k0 += 32) {
    f16x8 af[4], bf[4];
    #pragma unroll
    for (int mt = 0; mt < 4; ++mt)
      af[mt] = *(const f16x8*)&sA[(mw + mt * 16 + lr) * 136 + k0 + lg * 8];
    #pragma unroll
    for (int nt = 0; nt < 4; ++nt)
      bf[nt] = *(const f16x8*)&sB[(nw + nt * 16 + lr) * 136 + k0 + lg * 8];
    #pragma unroll
    for (int mt = 0; mt < 4; ++mt)
      #pragma unroll
      for (int nt = 0; nt < 4; ++nt)
        acc[mt][nt] = MFMA16(af[mt], bf[nt], acc[mt][nt]);
  }
  #pragma unroll
  for (int mt = 0; mt < 4; ++mt)
    #pragma unroll
    for (int nt = 0; nt < 4; ++nt)
      #pragma unroll
      for (int r = 0; r < 4; ++r) {
        int row = m0 + mw + mt * 16 + lg * 4 + r;
        int col = nw + nt * 16 + lr;
        out[(size_t)row * 128 + col] = acc[mt][nt][r];
      }
}

// ---------------------------------------------------------------------------
extern "C" void kernel_launch(void* const* d_in, const int* in_sizes, int n_in,
                              void* d_out, int out_size, void* d_ws, size_t ws_size,
                              hipStream_t stream) {
  (void)in_sizes; (void)n_in; (void)out_size; (void)ws_size;
  const float* z    = (const float*)d_in[0];
  const float* gam  = (const float*)d_in[1];
  const float* bet  = (const float*)d_in[2];
  const float* Wq   = (const float*)d_in[3];
  const float* Wk   = (const float*)d_in[4];
  const float* Wv   = (const float*)d_in[5];
  const float* Wb   = (const float*)d_in[6];
  const float* Wg   = (const float*)d_in[7];
  const float* Wout = (const float*)d_in[8];

  char* ws = (char*)d_ws;
  _Float16* zln   = (_Float16*)(ws);                 // 16MB, reused as OG
  _Float16* Qb    = (_Float16*)(ws + SEGB);
  _Float16* Kb    = (_Float16*)(ws + SEGB * 2);
  _Float16* Vb    = (_Float16*)(ws + SEGB * 3);
  _Float16* Gb    = (_Float16*)(ws + SEGB * 4);
  float*    biasT = (float*)   (ws + SEGB * 5);      // 1MB [4][65536] j-major
  _Float16* WtAll = (_Float16*)(ws + SEGB * 5 + 1048576);  // 5*16384 f16

  k_ln<<<16404, 256, 0, stream>>>(z, gam, bet, Wb, Wq, Wk, Wv, Wg, Wout,
                                  zln, biasT, WtAll);
  k_proj<<<2048, 256, 0, stream>>>(zln, WtAll, Qb, Kb, Vb, Gb);
  k_attn<<<dim3(256, 4), 256, 0, stream>>>(Qb, Kb, Vb, Gb, biasT, zln);
  k_outp<<<512, 256, 0, stream>>>(zln, WtAll + 4 * 16384, (float*)d_out);
}

// Round 6
// 204.269 us; speedup vs baseline: 1.2917x; 1.2917x over previous
//
#include <hip/hip_runtime.h>

typedef _Float16 f16x8 __attribute__((ext_vector_type(8)));
typedef _Float16 f16x2 __attribute__((ext_vector_type(2)));
typedef float f32x4 __attribute__((ext_vector_type(4)));

#define MFMA16(a, b, c) __builtin_amdgcn_mfma_f32_16x16x32_f16(a, b, c, 0, 0, 0)

#define NROW 65536           // 256*256 rows
#define SEGB 16777216ull     // 16MB workspace segment
#define LOG2E 1.4426950408889634f

// ---------------------------------------------------------------------------
// Kernel 1: LayerNorm (fp32) -> z_ln f16 ; bias = z_ln @ Wb, stored j-major
// pre-scaled by log2(e):  biasT[h][j*256 + k] = bias[j][k]*log2e
// (attn then uses exp2 directly: exp2(log2e*(s+b) - m) == exp(s+b - m')).
// Blocks >= 16384 transpose+convert the 5 weight mats to f16 Wt[n][k].
// ---------------------------------------------------------------------------
__global__ __launch_bounds__(256) void k_ln(
    const float* __restrict__ z, const float* __restrict__ gamma,
    const float* __restrict__ beta, const float* __restrict__ Wb,
    const float* __restrict__ Wq, const float* __restrict__ Wk,
    const float* __restrict__ Wv, const float* __restrict__ Wg,
    const float* __restrict__ Wout,
    _Float16* __restrict__ zln, float* __restrict__ biasT,
    _Float16* __restrict__ WtAll)
{
  __shared__ _Float16 sw[32 * 136];
  int bid = blockIdx.x;
  if (bid < 16384) {
    int lane = threadIdx.x & 63;
    int w = threadIdx.x >> 6;
    int row = bid * 4 + w;
    float2 v = ((const float2*)(z + (size_t)row * 128))[lane];
    float s = v.x + v.y;
    #pragma unroll
    for (int m = 1; m < 64; m <<= 1) s += __shfl_xor(s, m);
    float mu = s * 0.0078125f;
    float dx = v.x - mu, dy = v.y - mu;
    float q = dx * dx + dy * dy;
    #pragma unroll
    for (int m = 1; m < 64; m <<= 1) q += __shfl_xor(q, m);
    float rs = rsqrtf(q * 0.0078125f + 1e-5f);
    float2 g2 = ((const float2*)gamma)[lane];
    float2 b2 = ((const float2*)beta)[lane];
    float y0 = dx * rs * g2.x + b2.x;
    float y1 = dy * rs * g2.y + b2.y;
    f16x2 pr; pr.x = (_Float16)y0; pr.y = (_Float16)y1;
    *(f16x2*)(zln + (size_t)row * 128 + 2 * lane) = pr;
    // bias = y . Wb[:,h]  (Wb row-major [128][4] -> float4 per row)
    float4 wb0 = ((const float4*)Wb)[2 * lane];
    float4 wb1 = ((const float4*)Wb)[2 * lane + 1];
    float pb0 = y0 * wb0.x + y1 * wb1.x;
    float pb1 = y0 * wb0.y + y1 * wb1.y;
    float pb2 = y0 * wb0.z + y1 * wb1.z;
    float pb3 = y0 * wb0.w + y1 * wb1.w;
    #pragma unroll
    for (int m = 1; m < 64; m <<= 1) {
      pb0 += __shfl_xor(pb0, m);
      pb1 += __shfl_xor(pb1, m);
      pb2 += __shfl_xor(pb2, m);
      pb3 += __shfl_xor(pb3, m);
    }
    if (lane == 0) {
      // row = j*256 + k ; store j-major, *log2e
      biasT[row] = pb0 * LOG2E;
      biasT[NROW + row] = pb1 * LOG2E;
      biasT[2 * NROW + row] = pb2 * LOG2E;
      biasT[3 * NROW + row] = pb3 * LOG2E;
    }
  } else {
    // weight transpose+convert: Wt_m[n][k] = W_m[k][n], f16
    int t = bid - 16384;            // 0..19 : 5 mats x 4 slabs of 32 n
    int mat = t >> 2, n0 = (t & 3) * 32;
    const float* src = (mat == 0) ? Wq : (mat == 1) ? Wk : (mat == 2) ? Wv
                       : (mat == 3) ? Wg : Wout;
    _Float16* dst = WtAll + mat * 16384;
    for (int it = 0; it < 16; ++it) {
      int e = threadIdx.x + it * 256;   // 4096 elems
      int c = e >> 5, j = e & 31;
      sw[j * 136 + c] = (_Float16)src[c * 128 + n0 + j];
    }
    __syncthreads();
    for (int it = 0; it < 2; ++it) {
      int ch = threadIdx.x + it * 256;  // 512 chunks of 8
      int n = ch >> 4, k8 = (ch & 15) * 8;
      *(int4*)(dst + (n0 + n) * 128 + k8) = *(const int4*)&sw[n * 136 + k8];
    }
  }
}

// ---------------------------------------------------------------------------
// Kernel 2: projections  out = z_ln @ W  for W in {Wq,Wk,Wv,Wg}, sigmoid
// fused for Wg.  128x128 tile, K=128 one shot, 4 waves of 64x64.
// Grid is 1-D 2048 with XCD-aware decode: the 4 by-variants of each m-tile
// get ids that are congruent mod 8 -> same XCD -> A-tile read once from HBM,
// 3x from that XCD's L2.
// ---------------------------------------------------------------------------
__global__ __launch_bounds__(256) void k_proj(
    const _Float16* __restrict__ A, const _Float16* __restrict__ WtAll,
    _Float16* __restrict__ Qb, _Float16* __restrict__ Kb,
    _Float16* __restrict__ Vb, _Float16* __restrict__ Gb)
{
  __shared__ _Float16 sA[128 * 136];
  __shared__ _Float16 sB[128 * 136];
  int e = blockIdx.x;                 // 0..2047
  int by = (e >> 3) & 3;              // mat select
  int xb = ((e >> 5) << 3) | (e & 7); // m-tile, ids {g*32+by*8+xcd} share xcd
  int m0 = xb * 128;
  const _Float16* Bt = WtAll + by * 16384;
  _Float16* outp = (by == 0) ? Qb : (by == 1) ? Kb : (by == 2) ? Vb : Gb;
  int tid = threadIdx.x;
  for (int it = 0; it < 8; ++it) {
    int ch = tid + it * 256;           // 2048 chunks of 8 halfs
    int r = ch >> 4, c8 = (ch & 15) * 8;
    *(int4*)&sA[r * 136 + c8] = *(const int4*)(A + (size_t)(m0 + r) * 128 + c8);
    *(int4*)&sB[r * 136 + c8] = *(const int4*)(Bt + r * 128 + c8);
  }
  __syncthreads();
  int lane = tid & 63, w = tid >> 6;
  int mw = (w >> 1) * 64, nw = (w & 1) * 64;
  int lr = lane & 15, lg = lane >> 4;
  f32x4 z4 = {0.f, 0.f, 0.f, 0.f};
  f32x4 acc[4][4];
  #pragma unroll
  for (int mt = 0; mt < 4; ++mt)
    #pragma unroll
    for (int nt = 0; nt < 4; ++nt) acc[mt][nt] = z4;
  #pragma unroll
  for (int k0 = 0; k0 < 128; k0 += 32) {
    f16x8 af[4], bf[4];
    #pragma unroll
    for (int mt = 0; mt < 4; ++mt)
      af[mt] = *(const f16x8*)&sA[(mw + mt * 16 + lr) * 136 + k0 + lg * 8];
    #pragma unroll
    for (int nt = 0; nt < 4; ++nt)
      bf[nt] = *(const f16x8*)&sB[(nw + nt * 16 + lr) * 136 + k0 + lg * 8];
    #pragma unroll
    for (int mt = 0; mt < 4; ++mt)
      #pragma unroll
      for (int nt = 0; nt < 4; ++nt)
        acc[mt][nt] = MFMA16(af[mt], bf[nt], acc[mt][nt]);
  }
  bool sig = (by == 3);
  #pragma unroll
  for (int mt = 0; mt < 4; ++mt)
    #pragma unroll
    for (int nt = 0; nt < 4; ++nt)
      #pragma unroll
      for (int r = 0; r < 4; ++r) {
        int row = m0 + mw + mt * 16 + lg * 4 + r;
        int col = nw + nt * 16 + lr;
        float v = acc[mt][nt][r];
        if (sig) v = 1.0f / (1.0f + __expf(-v));
        outp[(size_t)row * 128 + col] = (_Float16)v;
      }
}

// ---------------------------------------------------------------------------
// Kernel 3: attention per (i,h) — ROUND-0 PROVEN STRUCTURE (64.4us), restored.
// Q as A-operand, P staged in LDS (sP), 64KB LDS, ~120 VGPR, no spill.
// Journal: rounds 1-5 tried register-resident P (swapped QK^T); the MFMA
// accumulators live in AGPRs of the unified file, so true reg footprint was
// >256 (occupancy 10%) or, when capped, spilled 290MB to scratch. LDS-P wins.
// Changes vs round 0: exp2f with log2e-prescaled bias (saves 1 mul/elem and
// uses the native exp2 pipe), s_setprio(1) around MFMA clusters (T5: +4-7%
// on barrier-free multi-wave attn, m191).
// ---------------------------------------------------------------------------
__global__ __launch_bounds__(256) void k_attn(
    const _Float16* __restrict__ Qb, const _Float16* __restrict__ Kb,
    const _Float16* __restrict__ Vb, const _Float16* __restrict__ Gb,
    const float* __restrict__ biasT, _Float16* __restrict__ OG)
{
  __shared__ _Float16 sK[256 * 32];   // [k][d], chunk-swizzled
  __shared__ _Float16 sV[32 * 256];   // Vt [d][k], chunk-swizzled
  __shared__ _Float16 sP[64 * 256];   // P  [j][k], chunk-swizzled
  int i = blockIdx.x, h = blockIdx.y;
  int tid = threadIdx.x;
  size_t base = ((size_t)i * 256) * 128 + h * 32;
  // stage K: row r, chunk cx -> phys cx ^ ((r>>1)&3)
  for (int it = 0; it < 4; ++it) {
    int ch = tid + it * 256;          // 1024 chunks
    int r = ch >> 2, cx = ch & 3;
    int p = cx ^ ((r >> 1) & 3);
    *(int4*)&sK[r * 32 + p * 8] = *(const int4*)(Kb + base + (size_t)r * 128 + cx * 8);
  }
  // stage V transposed: Vt[d][k], chunk (k>>3) -> phys ^ (d&7)
  for (int it = 0; it < 4; ++it) {
    int ch = tid + it * 256;
    int k = ch >> 2, d8 = (ch & 3) * 8;
    f16x8 tv = *(const f16x8*)(Vb + base + (size_t)k * 128 + d8);
    #pragma unroll
    for (int jj = 0; jj < 8; ++jj) {
      int d = d8 + jj;
      int p = (k >> 3) ^ (d & 7);
      sV[d * 256 + p * 8 + (k & 7)] = tv[jj];
    }
  }
  __syncthreads();
  int lane = tid & 63, w = tid >> 6;
  int lr = lane & 15, lg = lane >> 4;
  const float scale = 0.2550348858f;  // log2(e)/sqrt(32)
  f32x4 z4 = {0.f, 0.f, 0.f, 0.f};
  for (int pass = 0; pass < 4; ++pass) {
    int jbase = pass * 64;
    // Q fragment straight from global (each row used once)
    int jq = jbase + w * 16 + lr;
    f16x8 aq = *(const f16x8*)(Qb + base + (size_t)jq * 128 + lg * 8);
    f32x4 sacc[16];
    __builtin_amdgcn_s_setprio(1);
    #pragma unroll
    for (int kt = 0; kt < 16; ++kt) {
      int r = kt * 16 + lr;
      int p = lg ^ ((r >> 1) & 3);
      f16x8 bk = *(const f16x8*)&sK[r * 32 + p * 8];
      sacc[kt] = MFMA16(aq, bk, z4);
    }
    __builtin_amdgcn_s_setprio(0);
    // scale + bias (pre-scaled by log2e) + softmax over k (fp32), P -> LDS f16
    #pragma unroll
    for (int r = 0; r < 4; ++r) {
      int j = jbase + w * 16 + lg * 4 + r;
      const float* brow = biasT + (size_t)h * NROW + (size_t)j * 256;
      float mx = -1e30f;
      #pragma unroll
      for (int kt = 0; kt < 16; ++kt) {
        float sv = sacc[kt][r] * scale + brow[kt * 16 + lr];
        sacc[kt][r] = sv;
        mx = fmaxf(mx, sv);
      }
      #pragma unroll
      for (int msk = 1; msk < 16; msk <<= 1) mx = fmaxf(mx, __shfl_xor(mx, msk));
      float sum = 0.f;
      #pragma unroll
      for (int kt = 0; kt < 16; ++kt) {
        float pv = exp2f(sacc[kt][r] - mx);
        sacc[kt][r] = pv;
        sum += pv;
      }
      #pragma unroll
      for (int msk = 1; msk < 16; msk <<= 1) sum += __shfl_xor(sum, msk);
      float rinv = 1.0f / sum;
      int row = w * 16 + lg * 4 + r;
      #pragma unroll
      for (int kt = 0; kt < 16; ++kt) {
        int k = kt * 16 + lr;
        int pch = (k >> 3) ^ (row & 7);
        sP[row * 256 + pch * 8 + (k & 7)] = (_Float16)(sacc[kt][r] * rinv);
      }
    }
    // O = P @ V   (wave reads only its own P rows -> no barrier needed)
    f32x4 oacc[2] = {z4, z4};
    int prow = w * 16 + lr;
    #pragma unroll
    for (int ks = 0; ks < 8; ++ks) {
      int c = ks * 4 + lg;
      f16x8 ap = *(const f16x8*)&sP[prow * 256 + (c ^ (prow & 7)) * 8];
      __builtin_amdgcn_s_setprio(1);
      #pragma unroll
      for (int nt = 0; nt < 2; ++nt) {
        int d = nt * 16 + lr;
        f16x8 bv = *(const f16x8*)&sV[d * 256 + (c ^ (d & 7)) * 8];
        oacc[nt] = MFMA16(ap, bv, oacc[nt]);
      }
      __builtin_amdgcn_s_setprio(0);
    }
    // gate with G (sigmoid already applied) and store
    #pragma unroll
    for (int nt = 0; nt < 2; ++nt)
      #pragma unroll
      for (int r = 0; r < 4; ++r) {
        int j = jbase + w * 16 + lg * 4 + r;
        int d = nt * 16 + lr;
        size_t idx = base + (size_t)j * 128 + d;
        float g = (float)Gb[idx];
        OG[idx] = (_Float16)(oacc[nt][r] * g);
      }
  }
}

// ---------------------------------------------------------------------------
// Kernel 4: out = OG @ Wout  (fp32 output)
// ---------------------------------------------------------------------------
__global__ __launch_bounds__(256) void k_outp(
    const _Float16* __restrict__ A, const _Float16* __restrict__ Bt,
    float* __restrict__ out)
{
  __shared__ _Float16 sA[128 * 136];
  __shared__ _Float16 sB[128 * 136];
  int m0 = blockIdx.x * 128;
  int tid = threadIdx.x;
  for (int it = 0; it < 8; ++it) {
    int ch = tid + it * 256;
    int r = ch >> 4, c8 = (ch & 15) * 8;
    *(int4*)&sA[r * 136 + c8] = *(const int4*)(A + (size_t)(m0 + r) * 128 + c8);
    *(int4*)&sB[r * 136 + c8] = *(const int4*)(Bt + r * 128 + c8);
  }
  __syncthreads();
  int lane = tid & 63, w = tid >> 6;
  int mw = (w >> 1) * 64, nw = (w & 1) * 64;
  int lr = lane & 15, lg = lane >> 4;
  f32x4 z4 = {0.f, 0.f, 0.f, 0.f};
  f32x4 acc[4][4];
  #pragma unroll
  for (int mt = 0; mt < 4; ++mt)
    #pragma unroll
    for (int nt = 0; nt < 4; ++nt) acc[mt][nt] = z4;
  #pragma unroll
  for (int k0 = 0; k0 < 128; k0 += 32) {
    f16x8 af[4], bf[4];
    #pragma unroll
    for (int mt = 0; mt < 4; ++mt)
      af[mt] = *(const f16x8*)&sA[(mw + mt * 16 + lr) * 136 + k0 + lg * 8];
    #pragma unroll
    for (int nt = 0; nt < 4; ++nt)
      bf[nt] = *(const f16x8*)&sB[(nw + nt * 16 + lr) * 136 + k0 + lg * 8];
    #pragma unroll
    for (int mt = 0; mt < 4; ++mt)
      #pragma unroll
      for (int nt = 0; nt < 4; ++nt)
        acc[mt][nt] = MFMA16(af[mt], bf[nt], acc[mt][nt]);
  }
  #pragma unroll
  for (int mt = 0; mt < 4; ++mt)
    #pragma unroll
    for (int nt = 0; nt < 4; ++nt)
      #pragma unroll
      for (int r = 0; r < 4; ++r) {
        int row = m0 + mw + mt * 16 + lg * 4 + r;
        int col = nw + nt * 16 + lr;
        out[(size_t)row * 128 + col] = acc[mt][nt][r];
      }
}

// ---------------------------------------------------------------------------
extern "C" void kernel_launch(void* const* d_in, const int* in_sizes, int n_in,
                              void* d_out, int out_size, void* d_ws, size_t ws_size,
                              hipStream_t stream) {
  (void)in_sizes; (void)n_in; (void)out_size; (void)ws_size;
  const float* z    = (const float*)d_in[0];
  const float* gam  = (const float*)d_in[1];
  const float* bet  = (const float*)d_in[2];
  const float* Wq   = (const float*)d_in[3];
  const float* Wk   = (const float*)d_in[4];
  const float* Wv   = (const float*)d_in[5];
  const float* Wb   = (const float*)d_in[6];
  const float* Wg   = (const float*)d_in[7];
  const float* Wout = (const float*)d_in[8];

  char* ws = (char*)d_ws;
  _Float16* zln   = (_Float16*)(ws);                 // 16MB, reused as OG
  _Float16* Qb    = (_Float16*)(ws + SEGB);
  _Float16* Kb    = (_Float16*)(ws + SEGB * 2);
  _Float16* Vb    = (_Float16*)(ws + SEGB * 3);
  _Float16* Gb    = (_Float16*)(ws + SEGB * 4);
  float*    biasT = (float*)   (ws + SEGB * 5);      // 1MB [4][65536] j-major
  _Float16* WtAll = (_Float16*)(ws + SEGB * 5 + 1048576);  // 5*16384 f16

  k_ln<<<16404, 256, 0, stream>>>(z, gam, bet, Wb, Wq, Wk, Wv, Wg, Wout,
                                  zln, biasT, WtAll);
  k_proj<<<2048, 256, 0, stream>>>(zln, WtAll, Qb, Kb, Vb, Gb);
  k_attn<<<dim3(256, 4), 256, 0, stream>>>(Qb, Kb, Vb, Gb, biasT, zln);
  k_outp<<<512, 256, 0, stream>>>(zln, WtAll + 4 * 16384, (float*)d_out);
}

// Round 8
// 193.361 us; speedup vs baseline: 1.3646x; 1.0564x over previous
//
#include <hip/hip_runtime.h>

typedef _Float16 f16x8 __attribute__((ext_vector_type(8)));
typedef _Float16 f16x2 __attribute__((ext_vector_type(2)));
typedef float f32x4 __attribute__((ext_vector_type(4)));

#define MFMA16(a, b, c) __builtin_amdgcn_mfma_f32_16x16x32_f16(a, b, c, 0, 0, 0)

#define NROW 65536           // 256*256 rows
#define SEGB 16777216ull     // 16MB workspace segment
#define LOG2E 1.4426950408889634f

// ---------------------------------------------------------------------------
// Kernel 1: LayerNorm (fp32) -> z_ln f16.  Bias moved OUT (round-7): the 4
// bias dot-products were 24 of 36 serial shuffle-reduce steps per row; bias
// is matmul-shaped -> now a 5th GEMM variant in k_proj.
// Blocks >= 16384 transpose+convert weights to f16 Wt[n][k]:
//   slabs 0..3 = Wq,Wk,Wv,Wg ; slab 4 = WbT (4x128, zero-padded to 128x128)
//   slab 5 = WoutT.
// ---------------------------------------------------------------------------
__global__ __launch_bounds__(256) void k_ln(
    const float* __restrict__ z, const float* __restrict__ gamma,
    const float* __restrict__ beta, const float* __restrict__ Wb,
    const float* __restrict__ Wq, const float* __restrict__ Wk,
    const float* __restrict__ Wv, const float* __restrict__ Wg,
    const float* __restrict__ Wout,
    _Float16* __restrict__ zln, float* __restrict__ biasT,
    _Float16* __restrict__ WtAll)
{
  __shared__ _Float16 sw[32 * 136];
  int bid = blockIdx.x;
  if (bid < 16384) {
    int lane = threadIdx.x & 63;
    int w = threadIdx.x >> 6;
    int row = bid * 4 + w;
    float2 v = ((const float2*)(z + (size_t)row * 128))[lane];
    float s = v.x + v.y;
    #pragma unroll
    for (int m = 1; m < 64; m <<= 1) s += __shfl_xor(s, m);
    float mu = s * 0.0078125f;
    float dx = v.x - mu, dy = v.y - mu;
    float q = dx * dx + dy * dy;
    #pragma unroll
    for (int m = 1; m < 64; m <<= 1) q += __shfl_xor(q, m);
    float rs = rsqrtf(q * 0.0078125f + 1e-5f);
    float2 g2 = ((const float2*)gamma)[lane];
    float2 b2 = ((const float2*)beta)[lane];
    float y0 = dx * rs * g2.x + b2.x;
    float y1 = dy * rs * g2.y + b2.y;
    f16x2 pr; pr.x = (_Float16)y0; pr.y = (_Float16)y1;
    *(f16x2*)(zln + (size_t)row * 128 + 2 * lane) = pr;
  } else if (bid < 16384 + 20) {
    // weight transpose+convert: Wt_m[n][k] = W_m[k][n], f16
    int t = bid - 16384;            // 0..19 : 5 mats x 4 slabs of 32 n
    int mat = t >> 2, n0 = (t & 3) * 32;
    const float* src = (mat == 0) ? Wq : (mat == 1) ? Wk : (mat == 2) ? Wv
                       : (mat == 3) ? Wg : Wout;
    _Float16* dst = WtAll + ((mat == 4) ? 5 : mat) * 16384;  // Wout -> slab 5
    for (int it = 0; it < 16; ++it) {
      int e = threadIdx.x + it * 256;   // 4096 elems
      int c = e >> 5, j = e & 31;
      sw[j * 136 + c] = (_Float16)src[c * 128 + n0 + j];
    }
    __syncthreads();
    for (int it = 0; it < 2; ++it) {
      int ch = threadIdx.x + it * 256;  // 512 chunks of 8
      int n = ch >> 4, k8 = (ch & 15) * 8;
      *(int4*)(dst + (n0 + n) * 128 + k8) = *(const int4*)&sw[n * 136 + k8];
    }
  } else {
    // slab 4: WbT[n][k] = Wb[k][n] for n<4, zero for n>=4 (B-operand pad)
    _Float16* dst = WtAll + 4 * 16384;
    for (int e = threadIdx.x; e < 16384; e += 256) {
      int n = e >> 7, k = e & 127;
      dst[e] = (n < 4) ? (_Float16)Wb[k * 4 + n] : (_Float16)0.f;
    }
  }
}

// ---------------------------------------------------------------------------
// Kernel 2: projections  out = z_ln @ W  for W in {Wq,Wk,Wv,Wg,Wb}, sigmoid
// fused for Wg; by==4 computes bias = z_ln @ Wb (only nt=0 column-tile live,
// runtime-guarded so register allocation is unchanged) and stores
// biasT[h][row]*log2e.  128x128 tile, K=128 one shot, 4 waves of 64x64.
// Grid 2560 1-D with XCD-aware decode: the 5 by-variants of each m-tile get
// ids congruent mod 8 -> same XCD -> A-tile read once from HBM.
// ---------------------------------------------------------------------------
__global__ __launch_bounds__(256) void k_proj(
    const _Float16* __restrict__ A, const _Float16* __restrict__ WtAll,
    _Float16* __restrict__ Qb, _Float16* __restrict__ Kb,
    _Float16* __restrict__ Vb, _Float16* __restrict__ Gb,
    float* __restrict__ biasT)
{
  __shared__ _Float16 sA[128 * 136];
  __shared__ _Float16 sB[128 * 136];
  int e = blockIdx.x;                 // 0..2559
  int xcd = e & 7;
  int t = e >> 3;                     // 0..319
  int by = t % 5;                     // mat select (0..4)
  int g = t / 5;                      // 0..63
  int m0 = (g * 8 + xcd) * 128;
  const _Float16* Bt = WtAll + by * 16384;
  _Float16* outp = (by == 0) ? Qb : (by == 1) ? Kb : (by == 2) ? Vb : Gb;
  int tid = threadIdx.x;
  for (int it = 0; it < 8; ++it) {
    int ch = tid + it * 256;           // 2048 chunks of 8 halfs
    int r = ch >> 4, c8 = (ch & 15) * 8;
    *(int4*)&sA[r * 136 + c8] = *(const int4*)(A + (size_t)(m0 + r) * 128 + c8);
    *(int4*)&sB[r * 136 + c8] = *(const int4*)(Bt + r * 128 + c8);
  }
  __syncthreads();
  int lane = tid & 63, w = tid >> 6;
  int mw = (w >> 1) * 64, nw = (w & 1) * 64;
  int lr = lane & 15, lg = lane >> 4;
  int ntm = (by == 4) ? 1 : 4;        // bias blocks: only nt=0 column-tile
  f32x4 z4 = {0.f, 0.f, 0.f, 0.f};
  f32x4 acc[4][4];
  #pragma unroll
  for (int mt = 0; mt < 4; ++mt)
    #pragma unroll
    for (int nt = 0; nt < 4; ++nt) acc[mt][nt] = z4;
  #pragma unroll
  for (int k0 = 0; k0 < 128; k0 += 32) {
    f16x8 af[4], bf[4];
    #pragma unroll
    for (int mt = 0; mt < 4; ++mt)
      af[mt] = *(const f16x8*)&sA[(mw + mt * 16 + lr) * 136 + k0 + lg * 8];
    #pragma unroll
    for (int nt = 0; nt < 4; ++nt)
      if (nt < ntm)
        bf[nt] = *(const f16x8*)&sB[(nw + nt * 16 + lr) * 136 + k0 + lg * 8];
    #pragma unroll
    for (int mt = 0; mt < 4; ++mt)
      #pragma unroll
      for (int nt = 0; nt < 4; ++nt)
        if (nt < ntm)
          acc[mt][nt] = MFMA16(af[mt], bf[nt], acc[mt][nt]);
  }
  if (by == 4) {
    // bias epilogue: out[row][col] = bias[row][h=col], col=lr (valid <4),
    // only nw==0 waves hold it.  Store h-major, *log2e.
    if (nw == 0 && lr < 4) {
      #pragma unroll
      for (int mt = 0; mt < 4; ++mt)
        #pragma unroll
        for (int r = 0; r < 4; ++r) {
          int row = m0 + mw + mt * 16 + lg * 4 + r;
          biasT[(size_t)lr * NROW + row] = acc[mt][0][r] * LOG2E;
        }
    }
    return;
  }
  bool sig = (by == 3);
  #pragma unroll
  for (int mt = 0; mt < 4; ++mt)
    #pragma unroll
    for (int nt = 0; nt < 4; ++nt)
      #pragma unroll
      for (int r = 0; r < 4; ++r) {
        int row = m0 + mw + mt * 16 + lg * 4 + r;
        int col = nw + nt * 16 + lr;
        float v = acc[mt][nt][r];
        if (sig) v = 1.0f / (1.0f + __expf(-v));
        outp[(size_t)row * 128 + col] = (_Float16)v;
      }
}

// ---------------------------------------------------------------------------
// Kernel 3: attention per (i,h) — PROVEN STRUCTURE (61us, VGPR 124, no
// spill).  UNTOUCHED this round (control).  Q as A-operand, P staged in LDS,
// 64KB LDS.  Journal: rounds 1-5 proved register-resident P is infeasible
// here (unified VGPR+AGPR file -> >256 regs or 290MB scratch spill).
// ---------------------------------------------------------------------------
__global__ __launch_bounds__(256) void k_attn(
    const _Float16* __restrict__ Qb, const _Float16* __restrict__ Kb,
    const _Float16* __restrict__ Vb, const _Float16* __restrict__ Gb,
    const float* __restrict__ biasT, _Float16* __restrict__ OG)
{
  __shared__ _Float16 sK[256 * 32];   // [k][d], chunk-swizzled
  __shared__ _Float16 sV[32 * 256];   // Vt [d][k], chunk-swizzled
  __shared__ _Float16 sP[64 * 256];   // P  [j][k], chunk-swizzled
  int i = blockIdx.x, h = blockIdx.y;
  int tid = threadIdx.x;
  size_t base = ((size_t)i * 256) * 128 + h * 32;
  // stage K: row r, chunk cx -> phys cx ^ ((r>>1)&3)
  for (int it = 0; it < 4; ++it) {
    int ch = tid + it * 256;          // 1024 chunks
    int r = ch >> 2, cx = ch & 3;
    int p = cx ^ ((r >> 1) & 3);
    *(int4*)&sK[r * 32 + p * 8] = *(const int4*)(Kb + base + (size_t)r * 128 + cx * 8);
  }
  // stage V transposed: Vt[d][k], chunk (k>>3) -> phys ^ (d&7)
  for (int it = 0; it < 4; ++it) {
    int ch = tid + it * 256;
    int k = ch >> 2, d8 = (ch & 3) * 8;
    f16x8 tv = *(const f16x8*)(Vb + base + (size_t)k * 128 + d8);
    #pragma unroll
    for (int jj = 0; jj < 8; ++jj) {
      int d = d8 + jj;
      int p = (k >> 3) ^ (d & 7);
      sV[d * 256 + p * 8 + (k & 7)] = tv[jj];
    }
  }
  __syncthreads();
  int lane = tid & 63, w = tid >> 6;
  int lr = lane & 15, lg = lane >> 4;
  const float scale = 0.2550348858f;  // log2(e)/sqrt(32)
  f32x4 z4 = {0.f, 0.f, 0.f, 0.f};
  for (int pass = 0; pass < 4; ++pass) {
    int jbase = pass * 64;
    // Q fragment straight from global (each row used once)
    int jq = jbase + w * 16 + lr;
    f16x8 aq = *(const f16x8*)(Qb + base + (size_t)jq * 128 + lg * 8);
    f32x4 sacc[16];
    __builtin_amdgcn_s_setprio(1);
    #pragma unroll
    for (int kt = 0; kt < 16; ++kt) {
      int r = kt * 16 + lr;
      int p = lg ^ ((r >> 1) & 3);
      f16x8 bk = *(const f16x8*)&sK[r * 32 + p * 8];
      sacc[kt] = MFMA16(aq, bk, z4);
    }
    __builtin_amdgcn_s_setprio(0);
    // scale + bias (pre-scaled by log2e) + softmax over k (fp32), P -> LDS f16
    #pragma unroll
    for (int r = 0; r < 4; ++r) {
      int j = jbase + w * 16 + lg * 4 + r;
      const float* brow = biasT + (size_t)h * NROW + (size_t)j * 256;
      float mx = -1e30f;
      #pragma unroll
      for (int kt = 0; kt < 16; ++kt) {
        float sv = sacc[kt][r] * scale + brow[kt * 16 + lr];
        sacc[kt][r] = sv;
        mx = fmaxf(mx, sv);
      }
      #pragma unroll
      for (int msk = 1; msk < 16; msk <<= 1) mx = fmaxf(mx, __shfl_xor(mx, msk));
      float sum = 0.f;
      #pragma unroll
      for (int kt = 0; kt < 16; ++kt) {
        float pv = exp2f(sacc[kt][r] - mx);
        sacc[kt][r] = pv;
        sum += pv;
      }
      #pragma unroll
      for (int msk = 1; msk < 16; msk <<= 1) sum += __shfl_xor(sum, msk);
      float rinv = 1.0f / sum;
      int row = w * 16 + lg * 4 + r;
      #pragma unroll
      for (int kt = 0; kt < 16; ++kt) {
        int k = kt * 16 + lr;
        int pch = (k >> 3) ^ (row & 7);
        sP[row * 256 + pch * 8 + (k & 7)] = (_Float16)(sacc[kt][r] * rinv);
      }
    }
    // O = P @ V   (wave reads only its own P rows -> no barrier needed)
    f32x4 oacc[2] = {z4, z4};
    int prow = w * 16 + lr;
    #pragma unroll
    for (int ks = 0; ks < 8; ++ks) {
      int c = ks * 4 + lg;
      f16x8 ap = *(const f16x8*)&sP[prow * 256 + (c ^ (prow & 7)) * 8];
      __builtin_amdgcn_s_setprio(1);
      #pragma unroll
      for (int nt = 0; nt < 2; ++nt) {
        int d = nt * 16 + lr;
        f16x8 bv = *(const f16x8*)&sV[d * 256 + (c ^ (d & 7)) * 8];
        oacc[nt] = MFMA16(ap, bv, oacc[nt]);
      }
      __builtin_amdgcn_s_setprio(0);
    }
    // gate with G (sigmoid already applied) and store
    #pragma unroll
    for (int nt = 0; nt < 2; ++nt)
      #pragma unroll
      for (int r = 0; r < 4; ++r) {
        int j = jbase + w * 16 + lg * 4 + r;
        int d = nt * 16 + lr;
        size_t idx = base + (size_t)j * 128 + d;
        float g = (float)Gb[idx];
        OG[idx] = (_Float16)(oacc[nt][r] * g);
      }
  }
}

// ---------------------------------------------------------------------------
// Kernel 4: out = OG @ Wout  (fp32 output)
// ---------------------------------------------------------------------------
__global__ __launch_bounds__(256) void k_outp(
    const _Float16* __restrict__ A, const _Float16* __restrict__ Bt,
    float* __restrict__ out)
{
  __shared__ _Float16 sA[128 * 136];
  __shared__ _Float16 sB[128 * 136];
  int m0 = blockIdx.x * 128;
  int tid = threadIdx.x;
  for (int it = 0; it < 8; ++it) {
    int ch = tid + it * 256;
    int r = ch >> 4, c8 = (ch & 15) * 8;
    *(int4*)&sA[r * 136 + c8] = *(const int4*)(A + (size_t)(m0 + r) * 128 + c8);
    *(int4*)&sB[r * 136 + c8] = *(const int4*)(Bt + r * 128 + c8);
  }
  __syncthreads();
  int lane = tid & 63, w = tid >> 6;
  int mw = (w >> 1) * 64, nw = (w & 1) * 64;
  int lr = lane & 15, lg = lane >> 4;
  f32x4 z4 = {0.f, 0.f, 0.f, 0.f};
  f32x4 acc[4][4];
  #pragma unroll
  for (int mt = 0; mt < 4; ++mt)
    #pragma unroll
    for (int nt = 0; nt < 4; ++nt) acc[mt][nt] = z4;
  #pragma unroll
  for (int k0 = 0; k0 < 128; k0 += 32) {
    f16x8 af[4], bf[4];
    #pragma unroll
    for (int mt = 0; mt < 4; ++mt)
      af[mt] = *(const f16x8*)&sA[(mw + mt * 16 + lr) * 136 + k0 + lg * 8];
    #pragma unroll
    for (int nt = 0; nt < 4; ++nt)
      bf[nt] = *(const f16x8*)&sB[(nw + nt * 16 + lr) * 136 + k0 + lg * 8];
    #pragma unroll
    for (int mt = 0; mt < 4; ++mt)
      #pragma unroll
      for (int nt = 0; nt < 4; ++nt)
        acc[mt][nt] = MFMA16(af[mt], bf[nt], acc[mt][nt]);
  }
  #pragma unroll
  for (int mt = 0; mt < 4; ++mt)
    #pragma unroll
    for (int nt = 0; nt < 4; ++nt)
      #pragma unroll
      for (int r = 0; r < 4; ++r) {
        int row = m0 + mw + mt * 16 + lg * 4 + r;
        int col = nw + nt * 16 + lr;
        out[(size_t)row * 128 + col] = acc[mt][nt][r];
      }
}

// ---------------------------------------------------------------------------
extern "C" void kernel_launch(void* const* d_in, const int* in_sizes, int n_in,
                              void* d_out, int out_size, void* d_ws, size_t ws_size,
                              hipStream_t stream) {
  (void)in_sizes; (void)n_in; (void)out_size; (void)ws_size;
  const float* z    = (const float*)d_in[0];
  const float* gam  = (const float*)d_in[1];
  const float* bet  = (const float*)d_in[2];
  const float* Wq   = (const float*)d_in[3];
  const float* Wk   = (const float*)d_in[4];
  const float* Wv   = (const float*)d_in[5];
  const float* Wb   = (const float*)d_in[6];
  const float* Wg   = (const float*)d_in[7];
  const float* Wout = (const float*)d_in[8];

  char* ws = (char*)d_ws;
  _Float16* zln   = (_Float16*)(ws);                 // 16MB, reused as OG
  _Float16* Qb    = (_Float16*)(ws + SEGB);
  _Float16* Kb    = (_Float16*)(ws + SEGB * 2);
  _Float16* Vb    = (_Float16*)(ws + SEGB * 3);
  _Float16* Gb    = (_Float16*)(ws + SEGB * 4);
  float*    biasT = (float*)   (ws + SEGB * 5);      // 1MB [4][65536] h-major
  _Float16* WtAll = (_Float16*)(ws + SEGB * 5 + 1048576);  // 6*16384 f16

  k_ln<<<16405, 256, 0, stream>>>(z, gam, bet, Wb, Wq, Wk, Wv, Wg, Wout,
                                  zln, biasT, WtAll);
  k_proj<<<2560, 256, 0, stream>>>(zln, WtAll, Qb, Kb, Vb, Gb, biasT);
  k_attn<<<dim3(256, 4), 256, 0, stream>>>(Qb, Kb, Vb, Gb, biasT, zln);
  k_outp<<<512, 256, 0, stream>>>(zln, WtAll + 5 * 16384, (float*)d_out);
}

// Round 9
// 191.955 us; speedup vs baseline: 1.3746x; 1.0073x over previous
//
#include <hip/hip_runtime.h>

typedef _Float16 f16x8 __attribute__((ext_vector_type(8)));
typedef _Float16 f16x2 __attribute__((ext_vector_type(2)));
typedef float f32x4 __attribute__((ext_vector_type(4)));

#define MFMA16(a, b, c) __builtin_amdgcn_mfma_f32_16x16x32_f16(a, b, c, 0, 0, 0)

#define NROW 65536           // 256*256 rows
#define SEGB 16777216ull     // 16MB workspace segment
#define LOG2E 1.4426950408889634f

// ---------------------------------------------------------------------------
// Kernel 1: LayerNorm (fp32) -> z_ln f16.  Bias is a 5th GEMM variant in
// k_proj (round-8 win, -11us).  Blocks >= 16384 transpose+convert weights to
// f16 Wt[n][k]: slabs 0..3 = Wq,Wk,Wv,Wg ; slab 4 = WbT (zero-padded) ;
// slab 5 = WoutT.
// ---------------------------------------------------------------------------
__global__ __launch_bounds__(256) void k_ln(
    const float* __restrict__ z, const float* __restrict__ gamma,
    const float* __restrict__ beta, const float* __restrict__ Wb,
    const float* __restrict__ Wq, const float* __restrict__ Wk,
    const float* __restrict__ Wv, const float* __restrict__ Wg,
    const float* __restrict__ Wout,
    _Float16* __restrict__ zln, float* __restrict__ biasT,
    _Float16* __restrict__ WtAll)
{
  __shared__ _Float16 sw[32 * 136];
  int bid = blockIdx.x;
  if (bid < 16384) {
    int lane = threadIdx.x & 63;
    int w = threadIdx.x >> 6;
    int row = bid * 4 + w;
    float2 v = ((const float2*)(z + (size_t)row * 128))[lane];
    float s = v.x + v.y;
    #pragma unroll
    for (int m = 1; m < 64; m <<= 1) s += __shfl_xor(s, m);
    float mu = s * 0.0078125f;
    float dx = v.x - mu, dy = v.y - mu;
    float q = dx * dx + dy * dy;
    #pragma unroll
    for (int m = 1; m < 64; m <<= 1) q += __shfl_xor(q, m);
    float rs = rsqrtf(q * 0.0078125f + 1e-5f);
    float2 g2 = ((const float2*)gamma)[lane];
    float2 b2 = ((const float2*)beta)[lane];
    float y0 = dx * rs * g2.x + b2.x;
    float y1 = dy * rs * g2.y + b2.y;
    f16x2 pr; pr.x = (_Float16)y0; pr.y = (_Float16)y1;
    *(f16x2*)(zln + (size_t)row * 128 + 2 * lane) = pr;
  } else if (bid < 16384 + 20) {
    // weight transpose+convert: Wt_m[n][k] = W_m[k][n], f16
    int t = bid - 16384;            // 0..19 : 5 mats x 4 slabs of 32 n
    int mat = t >> 2, n0 = (t & 3) * 32;
    const float* src = (mat == 0) ? Wq : (mat == 1) ? Wk : (mat == 2) ? Wv
                       : (mat == 3) ? Wg : Wout;
    _Float16* dst = WtAll + ((mat == 4) ? 5 : mat) * 16384;  // Wout -> slab 5
    for (int it = 0; it < 16; ++it) {
      int e = threadIdx.x + it * 256;   // 4096 elems
      int c = e >> 5, j = e & 31;
      sw[j * 136 + c] = (_Float16)src[c * 128 + n0 + j];
    }
    __syncthreads();
    for (int it = 0; it < 2; ++it) {
      int ch = threadIdx.x + it * 256;  // 512 chunks of 8
      int n = ch >> 4, k8 = (ch & 15) * 8;
      *(int4*)(dst + (n0 + n) * 128 + k8) = *(const int4*)&sw[n * 136 + k8];
    }
  } else {
    // slab 4: WbT[n][k] = Wb[k][n] for n<4, zero for n>=4 (B-operand pad)
    _Float16* dst = WtAll + 4 * 16384;
    for (int e = threadIdx.x; e < 16384; e += 256) {
      int n = e >> 7, k = e & 127;
      dst[e] = (n < 4) ? (_Float16)Wb[k * 4 + n] : (_Float16)0.f;
    }
  }
}

// ---------------------------------------------------------------------------
// Kernel 2: projections  out = z_ln @ W  for W in {Wq,Wk,Wv,Wg,Wb}, sigmoid
// fused for Wg; by==4 computes bias = z_ln @ Wb and stores *log2e at the
// SIGMA-PERMUTED position (round-9): pos low-byte = sigma(k) = (k&15)<<4 |
// k>>4, so k_attn's 16 bias values per (j,lr) are contiguous -> float4 loads.
// Grid 2560 1-D with XCD-aware decode (5 by-variants of an m-tile share XCD).
// ---------------------------------------------------------------------------
__global__ __launch_bounds__(256) void k_proj(
    const _Float16* __restrict__ A, const _Float16* __restrict__ WtAll,
    _Float16* __restrict__ Qb, _Float16* __restrict__ Kb,
    _Float16* __restrict__ Vb, _Float16* __restrict__ Gb,
    float* __restrict__ biasT)
{
  __shared__ _Float16 sA[128 * 136];
  __shared__ _Float16 sB[128 * 136];
  int e = blockIdx.x;                 // 0..2559
  int xcd = e & 7;
  int t = e >> 3;                     // 0..319
  int by = t % 5;                     // mat select (0..4)
  int g = t / 5;                      // 0..63
  int m0 = (g * 8 + xcd) * 128;
  const _Float16* Bt = WtAll + by * 16384;
  _Float16* outp = (by == 0) ? Qb : (by == 1) ? Kb : (by == 2) ? Vb : Gb;
  int tid = threadIdx.x;
  for (int it = 0; it < 8; ++it) {
    int ch = tid + it * 256;           // 2048 chunks of 8 halfs
    int r = ch >> 4, c8 = (ch & 15) * 8;
    *(int4*)&sA[r * 136 + c8] = *(const int4*)(A + (size_t)(m0 + r) * 128 + c8);
    *(int4*)&sB[r * 136 + c8] = *(const int4*)(Bt + r * 128 + c8);
  }
  __syncthreads();
  int lane = tid & 63, w = tid >> 6;
  int mw = (w >> 1) * 64, nw = (w & 1) * 64;
  int lr = lane & 15, lg = lane >> 4;
  int ntm = (by == 4) ? 1 : 4;        // bias blocks: only nt=0 column-tile
  f32x4 z4 = {0.f, 0.f, 0.f, 0.f};
  f32x4 acc[4][4];
  #pragma unroll
  for (int mt = 0; mt < 4; ++mt)
    #pragma unroll
    for (int nt = 0; nt < 4; ++nt) acc[mt][nt] = z4;
  #pragma unroll
  for (int k0 = 0; k0 < 128; k0 += 32) {
    f16x8 af[4], bf[4];
    #pragma unroll
    for (int mt = 0; mt < 4; ++mt)
      af[mt] = *(const f16x8*)&sA[(mw + mt * 16 + lr) * 136 + k0 + lg * 8];
    #pragma unroll
    for (int nt = 0; nt < 4; ++nt)
      if (nt < ntm)
        bf[nt] = *(const f16x8*)&sB[(nw + nt * 16 + lr) * 136 + k0 + lg * 8];
    #pragma unroll
    for (int mt = 0; mt < 4; ++mt)
      #pragma unroll
      for (int nt = 0; nt < 4; ++nt)
        if (nt < ntm)
          acc[mt][nt] = MFMA16(af[mt], bf[nt], acc[mt][nt]);
  }
  if (by == 4) {
    // bias epilogue: value bias(j,k) -> biasT[h][ j*256 + sigma(k) ], *log2e
    if (nw == 0 && lr < 4) {
      #pragma unroll
      for (int mt = 0; mt < 4; ++mt)
        #pragma unroll
        for (int r = 0; r < 4; ++r) {
          int row = m0 + mw + mt * 16 + lg * 4 + r;
          int lowk = row & 255;
          int pos = (row & ~255) | ((lowk & 15) << 4) | (lowk >> 4);
          biasT[(size_t)lr * NROW + pos] = acc[mt][0][r] * LOG2E;
        }
    }
    return;
  }
  bool sig = (by == 3);
  #pragma unroll
  for (int mt = 0; mt < 4; ++mt)
    #pragma unroll
    for (int nt = 0; nt < 4; ++nt)
      #pragma unroll
      for (int r = 0; r < 4; ++r) {
        int row = m0 + mw + mt * 16 + lg * 4 + r;
        int col = nw + nt * 16 + lr;
        float v = acc[mt][nt][r];
        if (sig) v = 1.0f / (1.0f + __expf(-v));
        outp[(size_t)row * 128 + col] = (_Float16)v;
      }
}

// ---------------------------------------------------------------------------
// Kernel 3: attention per (i,h).  Round-9: global k-permutation
// sigma(k) = (k&15)*16 + (k>>4) applied consistently to sP, sV and biasT.
// PV sums over k, so any fixed reorder of k is legal when P and V agree.
// Under sigma a lane's 16 softmax values (kt=0..15, fixed lr) are CONTIGUOUS:
//   - P-store: 2 x ds_write_b128 per row (was 16 scalar b16 stores)
//   - bias:    4 x float4 coalesced loads per row (was 16 scalar loads)
//   - rinv deferred to the gate epilogue (P stored unnormalized, <=1)
// PV / QK^T / sK code unchanged.  LDS 64KB -> 2 blocks/CU (VGPR-cliff-free:
// residency is LDS-capped, VGPR may grow to 256 without occupancy change).
// ---------------------------------------------------------------------------
__global__ __launch_bounds__(256) void k_attn(
    const _Float16* __restrict__ Qb, const _Float16* __restrict__ Kb,
    const _Float16* __restrict__ Vb, const _Float16* __restrict__ Gb,
    const float* __restrict__ biasT, _Float16* __restrict__ OG)
{
  __shared__ _Float16 sK[256 * 32];   // [k][d], chunk-swizzled
  __shared__ _Float16 sV[32 * 256];   // Vt [d][sigma(k)], chunk-swizzled
  __shared__ _Float16 sP[64 * 256];   // P  [j][sigma(k)], chunk-swizzled
  int i = blockIdx.x, h = blockIdx.y;
  int tid = threadIdx.x;
  size_t base = ((size_t)i * 256) * 128 + h * 32;
  // stage K: row r, chunk cx -> phys cx ^ ((r>>1)&3)   (k NOT permuted here)
  for (int it = 0; it < 4; ++it) {
    int ch = tid + it * 256;          // 1024 chunks
    int r = ch >> 2, cx = ch & 3;
    int p = cx ^ ((r >> 1) & 3);
    *(int4*)&sK[r * 32 + p * 8] = *(const int4*)(Kb + base + (size_t)r * 128 + cx * 8);
  }
  // stage V transposed+sigma-permuted: Vt[d][sigma(k)], chunk ^ (d&7)
  for (int it = 0; it < 4; ++it) {
    int ch = tid + it * 256;
    int k = ch >> 2, d8 = (ch & 3) * 8;
    f16x8 tv = *(const f16x8*)(Vb + base + (size_t)k * 128 + d8);
    int k2 = ((k & 15) << 4) | (k >> 4);
    int c2 = k2 >> 3, e2 = k2 & 7;
    #pragma unroll
    for (int jj = 0; jj < 8; ++jj) {
      int d = d8 + jj;
      int p = c2 ^ (d & 7);
      sV[d * 256 + p * 8 + e2] = tv[jj];
    }
  }
  __syncthreads();
  int lane = tid & 63, w = tid >> 6;
  int lr = lane & 15, lg = lane >> 4;
  const float scale = 0.2550348858f;  // log2(e)/sqrt(32)
  f32x4 z4 = {0.f, 0.f, 0.f, 0.f};
  for (int pass = 0; pass < 4; ++pass) {
    int jbase = pass * 64;
    // Q fragment straight from global (each row used once)
    int jq = jbase + w * 16 + lr;
    f16x8 aq = *(const f16x8*)(Qb + base + (size_t)jq * 128 + lg * 8);
    f32x4 sacc[16];
    __builtin_amdgcn_s_setprio(1);
    #pragma unroll
    for (int kt = 0; kt < 16; ++kt) {
      int r = kt * 16 + lr;
      int p = lg ^ ((r >> 1) & 3);
      f16x8 bk = *(const f16x8*)&sK[r * 32 + p * 8];
      sacc[kt] = MFMA16(aq, bk, z4);
    }
    __builtin_amdgcn_s_setprio(0);
    // softmax over k per row; bias is sigma-ordered -> 4 coalesced float4
    float rinv4[4];
    #pragma unroll
    for (int r = 0; r < 4; ++r) {
      int j = jbase + w * 16 + lg * 4 + r;
      const float* brow = biasT + (size_t)h * NROW + (size_t)j * 256 + lr * 16;
      float4 b4[4];
      #pragma unroll
      for (int m = 0; m < 4; ++m) b4[m] = ((const float4*)brow)[m];
      float mx = -1e30f;
      #pragma unroll
      for (int kt = 0; kt < 16; ++kt) {
        float bb = ((const float*)&b4[kt >> 2])[kt & 3];
        float sv = sacc[kt][r] * scale + bb;
        sacc[kt][r] = sv;
        mx = fmaxf(mx, sv);
      }
      #pragma unroll
      for (int msk = 1; msk < 16; msk <<= 1) mx = fmaxf(mx, __shfl_xor(mx, msk));
      float sum = 0.f;
      f16x8 h0, h1;
      #pragma unroll
      for (int kt = 0; kt < 16; ++kt) {
        float pv = exp2f(sacc[kt][r] - mx);
        sum += pv;
        if (kt < 8) h0[kt] = (_Float16)pv;
        else        h1[kt - 8] = (_Float16)pv;
      }
      #pragma unroll
      for (int msk = 1; msk < 16; msk <<= 1) sum += __shfl_xor(sum, msk);
      rinv4[r] = 1.0f / sum;
      // sigma(kt*16+lr) = lr*16+kt -> 16 contiguous halfs = chunks 2lr,2lr+1
      int row = w * 16 + lg * 4 + r;
      *(f16x8*)&sP[row * 256 + ((2 * lr) ^ (row & 7)) * 8] = h0;
      *(f16x8*)&sP[row * 256 + ((2 * lr + 1) ^ (row & 7)) * 8] = h1;
    }
    // O = P @ V  (sigma-consistent windows; wave reads only its own P rows)
    f32x4 oacc[2] = {z4, z4};
    int prow = w * 16 + lr;
    #pragma unroll
    for (int ks = 0; ks < 8; ++ks) {
      int c = ks * 4 + lg;
      f16x8 ap = *(const f16x8*)&sP[prow * 256 + (c ^ (prow & 7)) * 8];
      __builtin_amdgcn_s_setprio(1);
      #pragma unroll
      for (int nt = 0; nt < 2; ++nt) {
        int d = nt * 16 + lr;
        f16x8 bv = *(const f16x8*)&sV[d * 256 + (c ^ (d & 7)) * 8];
        oacc[nt] = MFMA16(ap, bv, oacc[nt]);
      }
      __builtin_amdgcn_s_setprio(0);
    }
    // gate with G (sigmoid already applied), deferred normalize, store
    #pragma unroll
    for (int nt = 0; nt < 2; ++nt)
      #pragma unroll
      for (int r = 0; r < 4; ++r) {
        int j = jbase + w * 16 + lg * 4 + r;
        int d = nt * 16 + lr;
        size_t idx = base + (size_t)j * 128 + d;
        float g = (float)Gb[idx];
        OG[idx] = (_Float16)(oacc[nt][r] * rinv4[r] * g);
      }
  }
}

// ---------------------------------------------------------------------------
// Kernel 4: out = OG @ Wout  (fp32 output)
// ---------------------------------------------------------------------------
__global__ __launch_bounds__(256) void k_outp(
    const _Float16* __restrict__ A, const _Float16* __restrict__ Bt,
    float* __restrict__ out)
{
  __shared__ _Float16 sA[128 * 136];
  __shared__ _Float16 sB[128 * 136];
  int m0 = blockIdx.x * 128;
  int tid = threadIdx.x;
  for (int it = 0; it < 8; ++it) {
    int ch = tid + it * 256;
    int r = ch >> 4, c8 = (ch & 15) * 8;
    *(int4*)&sA[r * 136 + c8] = *(const int4*)(A + (size_t)(m0 + r) * 128 + c8);
    *(int4*)&sB[r * 136 + c8] = *(const int4*)(Bt + r * 128 + c8);
  }
  __syncthreads();
  int lane = tid & 63, w = tid >> 6;
  int mw = (w >> 1) * 64, nw = (w & 1) * 64;
  int lr = lane & 15, lg = lane >> 4;
  f32x4 z4 = {0.f, 0.f, 0.f, 0.f};
  f32x4 acc[4][4];
  #pragma unroll
  for (int mt = 0; mt < 4; ++mt)
    #pragma unroll
    for (int nt = 0; nt < 4; ++nt) acc[mt][nt] = z4;
  #pragma unroll
  for (int k0 = 0; k0 < 128; k0 += 32) {
    f16x8 af[4], bf[4];
    #pragma unroll
    for (int mt = 0; mt < 4; ++mt)
      af[mt] = *(const f16x8*)&sA[(mw + mt * 16 + lr) * 136 + k0 + lg * 8];
    #pragma unroll
    for (int nt = 0; nt < 4; ++nt)
      bf[nt] = *(const f16x8*)&sB[(nw + nt * 16 + lr) * 136 + k0 + lg * 8];
    #pragma unroll
    for (int mt = 0; mt < 4; ++mt)
      #pragma unroll
      for (int nt = 0; nt < 4; ++nt)
        acc[mt][nt] = MFMA16(af[mt], bf[nt], acc[mt][nt]);
  }
  #pragma unroll
  for (int mt = 0; mt < 4; ++mt)
    #pragma unroll
    for (int nt = 0; nt < 4; ++nt)
      #pragma unroll
      for (int r = 0; r < 4; ++r) {
        int row = m0 + mw + mt * 16 + lg * 4 + r;
        int col = nw + nt * 16 + lr;
        out[(size_t)row * 128 + col] = acc[mt][nt][r];
      }
}

// ---------------------------------------------------------------------------
extern "C" void kernel_launch(void* const* d_in, const int* in_sizes, int n_in,
                              void* d_out, int out_size, void* d_ws, size_t ws_size,
                              hipStream_t stream) {
  (void)in_sizes; (void)n_in; (void)out_size; (void)ws_size;
  const float* z    = (const float*)d_in[0];
  const float* gam  = (const float*)d_in[1];
  const float* bet  = (const float*)d_in[2];
  const float* Wq   = (const float*)d_in[3];
  const float* Wk   = (const float*)d_in[4];
  const float* Wv   = (const float*)d_in[5];
  const float* Wb   = (const float*)d_in[6];
  const float* Wg   = (const float*)d_in[7];
  const float* Wout = (const float*)d_in[8];

  char* ws = (char*)d_ws;
  _Float16* zln   = (_Float16*)(ws);                 // 16MB, reused as OG
  _Float16* Qb    = (_Float16*)(ws + SEGB);
  _Float16* Kb    = (_Float16*)(ws + SEGB * 2);
  _Float16* Vb    = (_Float16*)(ws + SEGB * 3);
  _Float16* Gb    = (_Float16*)(ws + SEGB * 4);
  float*    biasT = (float*)   (ws + SEGB * 5);      // 1MB [4][65536] sigma'd
  _Float16* WtAll = (_Float16*)(ws + SEGB * 5 + 1048576);  // 6*16384 f16

  k_ln<<<16405, 256, 0, stream>>>(z, gam, bet, Wb, Wq, Wk, Wv, Wg, Wout,
                                  zln, biasT, WtAll);
  k_proj<<<2560, 256, 0, stream>>>(zln, WtAll, Qb, Kb, Vb, Gb, biasT);
  k_attn<<<dim3(256, 4), 256, 0, stream>>>(Qb, Kb, Vb, Gb, biasT, zln);
  k_outp<<<512, 256, 0, stream>>>(zln, WtAll + 5 * 16384, (float*)d_out);
}